// Round 12
// baseline (108.019 us; speedup 1.0000x reference)
//
#include <hip/hip_runtime.h>
#include <hip/hip_fp16.h>
#include <math.h>

#define V_ 128
#define K_ 32
#define C_ 256
#define L_ 4
#define N_ 4096
#define F_ 16
#define E_ 8192
#define B_ 512
#define EPS_ 1e-6f

__device__ __forceinline__ __half2 u2h(unsigned u) {
    __half2 h; *reinterpret_cast<unsigned*>(&h) = u; return h;
}
__device__ __forceinline__ unsigned h2u(__half2 h) {
    return *reinterpret_cast<unsigned*>(&h);
}
__device__ __forceinline__ __half b2h(unsigned short u) {
    __half h; *reinterpret_cast<unsigned short*>(&h) = u; return h;
}
__device__ __forceinline__ unsigned short h2b(__half h) {
    return *reinterpret_cast<unsigned short*>(&h);
}
// ROCm has no __hmax2; exact packed max via lossless half->float round-trip.
__device__ __forceinline__ __half2 hmax2(__half2 a, __half2 b) {
    float2 fa = __half22float2(a), fb = __half22float2(b);
    return __floats2half2_rn(fmaxf(fa.x, fb.x), fmaxf(fa.y, fb.y));
}

// ---------------------------------------------------------------------------
// Fused prep kernel (one launch, 1217 blocks x 256 threads):
//  [0,64):      PIW[l][n][0..15] = {sc16 | half_bits(w)<<16}, BANK-SORTED by
//               (sc&31) and staggered by (n&15): at mega gather-instr s the
//               64 lanes of a wave read stratified bank-quantiles instead of
//               i.i.d. random banks -> worst-bank load ~6 -> ~3.
//  [64,192):    PP[l][e] = c0 | c1<<16  (product children, L*E entries)
//  [192,1216):  inv_row[n] = 1/Σ_c(ip[n,c]+EPS)   (4 rows/block)
//  block 1216:  lrpsum = log(Σ_n(rp[n]+EPS))
// ---------------------------------------------------------------------------
__global__ __launch_bounds__(256) void prep_kernel(const float* __restrict__ sp,
                                                   const int* __restrict__ prod,
                                                   const int* __restrict__ sc,
                                                   const float* __restrict__ ip,
                                                   const float* __restrict__ rp,
                                                   unsigned* __restrict__ PIW,
                                                   unsigned* __restrict__ PP,
                                                   float* __restrict__ inv_row,
                                                   float* __restrict__ lrpsum) {
    int blk = blockIdx.x;
    int tid = threadIdx.x;
    if (blk < 64) {
        int idx = blk * 256 + tid;          // (l,n), L*N = 16384
        const float4* row4 = (const float4*)(sp + (size_t)idx * F_);
        float v[F_];
        float s = 0.f;
#pragma unroll
        for (int q = 0; q < 4; q++) {
            float4 r = row4[q];
            v[4*q+0] = r.x + EPS_; v[4*q+1] = r.y + EPS_;
            v[4*q+2] = r.z + EPS_; v[4*q+3] = r.w + EPS_;
            s += v[4*q+0] + v[4*q+1] + v[4*q+2] + v[4*q+3];
        }
        float inv = 1.f / s;
        const int* scr = sc + (size_t)idx * F_;
        unsigned* dst  = PIW + (size_t)idx * F_;
        // pack (index, weight) and sort by LDS bank of the em-gather (e & 31)
        unsigned long long key[F_];
#pragma unroll
        for (int f = 0; f < F_; f++) {
            unsigned e     = (unsigned)(unsigned short)scr[f];
            unsigned wbits = h2b(__float2half(v[f] * inv));
            unsigned pk    = e | (wbits << 16);
            key[f] = ((unsigned long long)(e & 31u) << 32) | pk;
        }
        // odd-even transposition network, 16 rounds (static indices -> regs)
#pragma unroll
        for (int r = 0; r < 16; r++) {
#pragma unroll
            for (int i = 0; i < 15; i++) {
                if ((i & 1) == (r & 1)) {
                    unsigned long long a = key[i], b = key[i+1];
                    key[i]   = a < b ? a : b;
                    key[i+1] = a < b ? b : a;
                }
            }
        }
        int rot = idx & 15;                 // = n & 15
#pragma unroll
        for (int r = 0; r < 16; r++)
            dst[(r + rot) & 15] = (unsigned)key[r];
    } else if (blk < 192) {
        int idx = (blk - 64) * 256 + tid;   // (l,e), L*E = 32768
        int2 c  = ((const int2*)prod)[idx];
        PP[idx] = (unsigned)c.x | ((unsigned)c.y << 16);
    } else if (blk < 192 + 1024) {
        int rblk = blk - 192;
        int n    = rblk * 4 + (tid >> 6);
        int lane = tid & 63;
        const float* row = ip + (size_t)n * C_;
        float t = 0.f;
#pragma unroll
        for (int i = 0; i < 4; i++) t += row[lane + 64 * i] + EPS_;
#pragma unroll
        for (int off = 32; off; off >>= 1) t += __shfl_down(t, off, 64);
        if (lane == 0) inv_row[n] = 1.f / t;
    } else {
        __shared__ float smem[4];
        float acc = 0.f;
        for (int i = tid; i < N_; i += 256) acc += rp[i] + EPS_;
#pragma unroll
        for (int off = 32; off; off >>= 1) acc += __shfl_down(acc, off, 64);
        if ((tid & 63) == 0) smem[tid >> 6] = acc;
        __syncthreads();
        if (tid == 0) lrpsum[0] = __logf(smem[0] + smem[1] + smem[2] + smem[3]);
    }
}

#define FSTEP(QQ, ACC) { unsigned qq_ = (QQ); \
    ACC = __hfma2(u2h(em[qq_ & 0xffff]), \
                  __half2half2(b2h((unsigned short)(qq_ >> 16))), ACC); }

// ---------------------------------------------------------------------------
// Mega kernel: whole circuit per 2-wide b-slice, scaled-linear in LDS.
// R12 over R11: PIW entries are bank-sorted+staggered (see prep) and the sum
// stage uses DUAL accumulators (halved fp16-FMA dep chain).  Structure else
// identical: deferred renorm, memoized products, exact sigma bookkeeping.
// Grid = B/2 = 256 blocks x 1024 threads; LDS = 16+32 KB.
// ---------------------------------------------------------------------------
__global__ __launch_bounds__(1024) void mega_kernel(const float* __restrict__ ip,
                                                    const int* __restrict__ inputs,
                                                    const float* __restrict__ inv_row,
                                                    const float* __restrict__ rp,
                                                    const unsigned* __restrict__ PIW,
                                                    const unsigned* __restrict__ PP,
                                                    const float* __restrict__ lrpsum,
                                                    float* __restrict__ out) {
    __shared__ unsigned nm[N_];        // half2 (b0,b1) per sum node   (16 KB)
    __shared__ unsigned em[E_];        // half2 (b0,b1) per product    (32 KB)
    __shared__ unsigned redm[16];
    __shared__ float    redf[32];
    int tid  = threadIdx.x;
    int lane = tid & 63;
    int w    = tid >> 6;
    int b0   = blockIdx.x * 2, b1 = b0 + 1;

    // ---- input layer: linear u = (ip[n,x]+EPS)/rowsum, renorm by per-b max
    float2 u[4];
    float mx0 = 0.f, mx1 = 0.f;
#pragma unroll
    for (int p = 0; p < 4; p++) {
        int n  = p * 1024 + tid;
        int v  = n >> 5;                       // K = 32
        int x0 = inputs[b0 * V_ + v];
        int x1 = inputs[b1 * V_ + v];
        float invr = inv_row[n];
        u[p].x = (ip[(size_t)n * C_ + x0] + EPS_) * invr;
        u[p].y = (ip[(size_t)n * C_ + x1] + EPS_) * invr;
        mx0 = fmaxf(mx0, u[p].x);
        mx1 = fmaxf(mx1, u[p].y);
    }
#pragma unroll
    for (int off = 32; off; off >>= 1) {
        mx0 = fmaxf(mx0, __shfl_down(mx0, off, 64));
        mx1 = fmaxf(mx1, __shfl_down(mx1, off, 64));
    }
    if (lane == 0) { redf[w] = mx0; redf[16 + w] = mx1; }
    __syncthreads();
    float m0 = redf[0], m1 = redf[16];
#pragma unroll
    for (int i = 1; i < 16; i++) { m0 = fmaxf(m0, redf[i]); m1 = fmaxf(m1, redf[16 + i]); }
    float inv0 = 1.f / m0, inv1 = 1.f / m1;
    float sg0 = __logf(m0), sg1 = __logf(m1);   // true = stored * e^sigma
#pragma unroll
    for (int p = 0; p < 4; p++)
        nm[p * 1024 + tid] = h2u(__floats2half2_rn(u[p].x * inv0, u[p].y * inv1));
    __syncthreads();

    __half2 ha  = __floats2half2_rn(1.f, 1.f);   // deferred scale (this layer)
    float   af0 = 1.f, af1 = 1.f;                // its exact fp32 value

    // ---- layers 0..2: product (scale folded) -> sum (store unscaled) ------
    for (int l = 0; l < L_ - 1; l++) {
        const uint4* pp4 = (const uint4*)(PP + (size_t)l * E_);
#pragma unroll
        for (int p = 0; p < 2; p++) {
            uint4 c = pp4[p * 1024 + tid];
            int e   = (p * 1024 + tid) * 4;
            em[e+0] = h2u(__hmul2(__hmul2(u2h(nm[c.x & 0xffff]), ha),
                                  __hmul2(u2h(nm[c.x >> 16]), ha)));
            em[e+1] = h2u(__hmul2(__hmul2(u2h(nm[c.y & 0xffff]), ha),
                                  __hmul2(u2h(nm[c.y >> 16]), ha)));
            em[e+2] = h2u(__hmul2(__hmul2(u2h(nm[c.z & 0xffff]), ha),
                                  __hmul2(u2h(nm[c.z >> 16]), ha)));
            em[e+3] = h2u(__hmul2(__hmul2(u2h(nm[c.w & 0xffff]), ha),
                                  __hmul2(u2h(nm[c.w >> 16]), ha)));
        }
        sg0 = 2.f * sg0 + 2.f * __logf(af0);
        sg1 = 2.f * sg1 + 2.f * __logf(af1);
        __syncthreads();

        const unsigned* piw = PIW + (size_t)l * N_ * F_;
        __half2 hm = u2h(0u);
#pragma unroll
        for (int p = 0; p < 4; p++) {
            int n = p * 1024 + tid;
            const uint4* qv = (const uint4*)(piw + (size_t)n * F_);
            uint4 q0 = qv[0], q1 = qv[1], q2 = qv[2], q3 = qv[3];
            __half2 accA = u2h(0u), accB = u2h(0u);
            FSTEP(q0.x, accA) FSTEP(q0.y, accB) FSTEP(q0.z, accA) FSTEP(q0.w, accB)
            FSTEP(q1.x, accA) FSTEP(q1.y, accB) FSTEP(q1.z, accA) FSTEP(q1.w, accB)
            FSTEP(q2.x, accA) FSTEP(q2.y, accB) FSTEP(q2.z, accA) FSTEP(q2.w, accB)
            FSTEP(q3.x, accA) FSTEP(q3.y, accB) FSTEP(q3.z, accA) FSTEP(q3.w, accB)
            __half2 acc = __hadd2(accA, accB);
            nm[n] = h2u(acc);              // store unscaled (overlaps reduction)
            hm    = hmax2(hm, acc);
        }
#pragma unroll
        for (int off = 32; off; off >>= 1)
            hm = hmax2(hm, u2h(__shfl_down(h2u(hm), off, 64)));
        if (lane == 0) redm[w] = h2u(hm);
        __syncthreads();                   // redm ready AND nm writes visible
        __half2 M = u2h(redm[0]);
#pragma unroll
        for (int i = 1; i < 16; i++) M = hmax2(M, u2h(redm[i]));
        float M0 = __half2float(__low2half(M)), M1 = __half2float(__high2half(M));
        ha  = __floats2half2_rn(fminf(1.f / M0, 60000.f), fminf(1.f / M1, 60000.f));
        af0 = __half2float(__low2half(ha));
        af1 = __half2float(__high2half(ha));
        sg0 -= 2.f * __logf(af0);          // scale applied next product stage
        sg1 -= 2.f * __logf(af1);
    }

    // ---- layer 3: product (scale folded) -> sum fused with root dot -------
    {
        const uint4* pp4 = (const uint4*)(PP + (size_t)(L_ - 1) * E_);
#pragma unroll
        for (int p = 0; p < 2; p++) {
            uint4 c = pp4[p * 1024 + tid];
            int e   = (p * 1024 + tid) * 4;
            em[e+0] = h2u(__hmul2(__hmul2(u2h(nm[c.x & 0xffff]), ha),
                                  __hmul2(u2h(nm[c.x >> 16]), ha)));
            em[e+1] = h2u(__hmul2(__hmul2(u2h(nm[c.y & 0xffff]), ha),
                                  __hmul2(u2h(nm[c.y >> 16]), ha)));
            em[e+2] = h2u(__hmul2(__hmul2(u2h(nm[c.z & 0xffff]), ha),
                                  __hmul2(u2h(nm[c.z >> 16]), ha)));
            em[e+3] = h2u(__hmul2(__hmul2(u2h(nm[c.w & 0xffff]), ha),
                                  __hmul2(u2h(nm[c.w >> 16]), ha)));
        }
        sg0 = 2.f * sg0 + 2.f * __logf(af0);
        sg1 = 2.f * sg1 + 2.f * __logf(af1);
        __syncthreads();

        const unsigned* piw = PIW + (size_t)(L_ - 1) * N_ * F_;
        float S0 = 0.f, S1 = 0.f;
#pragma unroll
        for (int p = 0; p < 4; p++) {
            int n = p * 1024 + tid;
            const uint4* qv = (const uint4*)(piw + (size_t)n * F_);
            uint4 q0 = qv[0], q1 = qv[1], q2 = qv[2], q3 = qv[3];
            __half2 accA = u2h(0u), accB = u2h(0u);
            FSTEP(q0.x, accA) FSTEP(q0.y, accB) FSTEP(q0.z, accA) FSTEP(q0.w, accB)
            FSTEP(q1.x, accA) FSTEP(q1.y, accB) FSTEP(q1.z, accA) FSTEP(q1.w, accB)
            FSTEP(q2.x, accA) FSTEP(q2.y, accB) FSTEP(q2.z, accA) FSTEP(q2.w, accB)
            FSTEP(q3.x, accA) FSTEP(q3.y, accB) FSTEP(q3.z, accA) FSTEP(q3.w, accB)
            float2 vv = __half22float2(__hadd2(accA, accB));
            float  r  = rp[n] + EPS_;
            S0 += r * vv.x;
            S1 += r * vv.y;
        }
#pragma unroll
        for (int off = 32; off; off >>= 1) {
            S0 += __shfl_down(S0, off, 64);
            S1 += __shfl_down(S1, off, 64);
        }
        if (lane == 0) { redf[w] = S0; redf[16 + w] = S1; }
        __syncthreads();
        if (tid == 0) {
            float s0 = 0.f, s1 = 0.f;
#pragma unroll
            for (int i = 0; i < 16; i++) { s0 += redf[i]; s1 += redf[16 + i]; }
            float lr = lrpsum[0];
            out[b0] = __logf(s0) + sg0 - lr;
            out[b1] = __logf(s1) + sg1 - lr;
        }
    }
}

extern "C" void kernel_launch(void* const* d_in, const int* in_sizes, int n_in,
                              void* d_out, int out_size, void* d_ws, size_t ws_size,
                              hipStream_t stream) {
    const int*   inputs = (const int*)d_in[0];     // (B, V) int32
    const int*   prod   = (const int*)d_in[1];     // (L, E, 2) int32
    const int*   sc     = (const int*)d_in[2];     // (L, N, F) int32
    const float* ip     = (const float*)d_in[3];   // (V, K, C) f32
    const float* sp     = (const float*)d_in[4];   // (L, N, F) f32
    const float* rp     = (const float*)d_in[5];   // (N,) f32
    float* out = (float*)d_out;                    // (B,) f32

    unsigned* PIW     = (unsigned*)d_ws;                     // L*N*F u32 (1 MB)
    unsigned* PP      = PIW + (size_t)L_ * N_ * F_;          // L*E u32 (128 KB)
    float*    inv_row = (float*)(PP + (size_t)L_ * E_);      // N floats
    float*    lrpsum  = inv_row + N_;                        // 1 float

    prep_kernel<<<64 + 128 + 1024 + 1, 256, 0, stream>>>(sp, prod, sc, ip, rp,
                                                         PIW, PP, inv_row, lrpsum);
    mega_kernel<<<B_ / 2, 1024, 0, stream>>>(ip, inputs, inv_row, rp,
                                             PIW, PP, lrpsum, out);
}